// Round 3
// baseline (1109.779 us; speedup 1.0000x reference)
//
#include <hip/hip_runtime.h>
#include <hip/hip_bf16.h>
#include <hip/hip_fp16.h>

#define T_DIM 8192
#define H_DIM 3200
#define I_DIM 12800

typedef int v4i __attribute__((ext_vector_type(4)));
typedef int v16i __attribute__((ext_vector_type(16)));
typedef _Float16 h8 __attribute__((ext_vector_type(8)));

__device__ __forceinline__ void gload16(const void* g, void* l) {
    __builtin_amdgcn_global_load_lds(
        (const __attribute__((address_space(1))) unsigned int*)g,
        (__attribute__((address_space(3))) unsigned int*)l, 16, 0, 0);
}

// ---------------- int32 -> int8 repack (memory-bound) ----------------
__global__ __launch_bounds__(256) void repack_kernel(const int* __restrict__ src,
                                                     unsigned int* __restrict__ dst,
                                                     long n4) {
    long i = (long)blockIdx.x * blockDim.x + threadIdx.x;
    long stride = (long)gridDim.x * blockDim.x;
    for (; i < n4; i += stride) {
        int4 v = ((const int4*)src)[i];
        dst[i] = (unsigned int)((v.x & 255) | ((v.y & 255) << 8) |
                                ((v.z & 255) << 16) | ((v.w & 255) << 24));
    }
}

// ---------------- i8 GEMM, C[M][N] = A[M][K] * B[N][K]^T ----------------
// 256x256 tile, 512 threads = 8 waves (2M x 4N), per-wave 128x64 output via
// mfma_i32_32x32x32_i8. One phase per 64-byte K-half: {12 ds_read_b128; stage
// A&B of half h+3; barrier; lgkmcnt(0); setprio1; 16 MFMA; setprio0; vmcnt(8);
// barrier}. Ring of 4 LDS slots/operand (128 KiB). Counted gate: entering
// phase h, half h is resident, halves h+1,h+2 (8 loads) in flight.
//
// LDS placement (fixes round-2's 3.07e7 bank conflicts): global_load_lds dest
// is LINEAR; a bijection pi is folded into the per-lane GLOBAL source so that
// the fragment-read instruction is lane-for-lane address-identical to the
// round-1 pattern that measured 0 conflicts (one wave op reads a contiguous
// 1 KiB = 16 LDS-rows x 4 chunks, each 16 B exactly once):
//   LDS (block, half, r15, col) holds global (row = block*32+((q&1)<<4)+r15,
//   chunk = (half<<1)|(q>>1)),  q = col ^ ((r15>>1)&3).
// Read: lane L needs (row = L&31, chunk = half*2 + L>>5) -> within-block addr
//   half*1024 + (L&15)*64 + ((((L>>5)<<1|((L>>4)&1)) ^ (((L&15)>>1)&3))<<4).
// strideA/strideB in BYTES. EPI=0: fp16 out. EPI=1: fp32 of fp16-rounded.
// NO XCD swizzle (T1 reverted: L3-resident regime, it tripled FETCH_SIZE).
template <int EPI>
__global__ __launch_bounds__(512, 2) void gemm_i8_32x32(
    const signed char* __restrict__ A, long strideA,
    const signed char* __restrict__ B, long strideB,
    int Ntrue, int K, int ldc,
    const float* __restrict__ rowscale, const float* __restrict__ colscale,
    const float* __restrict__ bias, void* __restrict__ Cout) {
    __shared__ signed char lds[131072];
    signed char* ldsA = lds;           // 4 slots x 16384 B (8 blocks of 2 KiB)
    signed char* ldsB = lds + 65536;   // 4 slots x 16384 B

    const int tid = threadIdx.x;
    const int lane = tid & 63, wid = tid >> 6;
    const int wr = wid >> 2, wc = wid & 3;
    const int bm = blockIdx.x, bn = blockIdx.y;
    const long Arow0 = (long)bm * 256;
    const long Bcol0 = (long)bn * 256;

    // Staging: slot = 1024 chunks of 16 B; thread handles ch0 = tid and
    // ch1 = tid+512. LDS dest linear (ch*16); source row/chunk from pi.
    int g_row[2], g_cg[2];
#pragma unroll
    for (int u = 0; u < 2; ++u) {
        const int ch = tid + (u << 9);
        const int block = ch >> 7;
        const int p = ch & 127;
        const int half = (p >> 6) & 1;
        const int p6 = p & 63;
        const int r15 = p6 >> 2;
        const int col = p6 & 3;
        const int q = col ^ ((r15 >> 1) & 3);
        g_row[u] = block * 32 + ((q & 1) << 4) + r15;
        g_cg[u] = (half << 1) | (q >> 1);
    }
    const signed char* Ag0 = A + (Arow0 + g_row[0]) * strideA + g_cg[0] * 16;
    const signed char* Ag1 = A + (Arow0 + g_row[1]) * strideA + g_cg[1] * 16;
    const signed char* Bg0 = B + (Bcol0 + g_row[0]) * strideB + g_cg[0] * 16;
    const signed char* Bg1 = B + (Bcol0 + g_row[1]) * strideB + g_cg[1] * 16;
    const int d0 = tid * 16, d1 = (tid + 512) * 16;

    const int NH = K >> 6;  // number of 64-byte K-halves (phases)

#define STAGE_A(h)                                  \
    {                                               \
        const int hc_ = (h) < NH ? (h) : NH - 1;    \
        const long ko_ = (long)hc_ << 6;            \
        signed char* d_ = ldsA + (((h) & 3) << 14); \
        gload16(Ag0 + ko_, d_ + d0);                \
        gload16(Ag1 + ko_, d_ + d1);                \
    }
#define STAGE_B(h)                                  \
    {                                               \
        const int hc_ = (h) < NH ? (h) : NH - 1;    \
        const long ko_ = (long)hc_ << 6;            \
        signed char* d_ = ldsB + (((h) & 3) << 14); \
        gload16(Bg0 + ko_, d_ + d0);                \
        gload16(Bg1 + ko_, d_ + d1);                \
    }

    // Fragment read offsets (round-1-proven conflict-free pattern per 1 KiB).
    const int rl = lane & 31, qh = lane >> 5;
    const int r15 = rl & 15, qb = rl >> 4;
    const int colr = ((qh << 1) | qb) ^ ((r15 >> 1) & 3);
    const int roff = r15 * 64 + colr * 16;  // within-block, half 0; a1/b1: +1024
    const int aoff = (wr * 4) * 2048 + roff;  // + m*2048, m = 0..3
    const int boff = (wc * 2) * 2048 + roff;  // + n*2048, n = 0..1

    v16i acc[4][2] = {};

    // Prologue: stage halves 0,1,2 (12 loads); gate to 8 -> half 0 resident,
    // halves 1,2 in flight (steady-state invariant entering phase 0).
    STAGE_A(0); STAGE_B(0); STAGE_A(1); STAGE_B(1); STAGE_A(2); STAGE_B(2);
    asm volatile("s_waitcnt vmcnt(8)");
    __builtin_amdgcn_s_barrier();

    for (int h = 0; h < NH; ++h) {
        const signed char* sA = ldsA + ((h & 3) << 14);
        const signed char* sB = ldsB + ((h & 3) << 14);
        v4i a0[4], a1[4], b0[2], b1[2];
#pragma unroll
        for (int m = 0; m < 4; ++m) {
            a0[m] = *(const v4i*)(sA + aoff + m * 2048);
            a1[m] = *(const v4i*)(sA + aoff + m * 2048 + 1024);
        }
#pragma unroll
        for (int n = 0; n < 2; ++n) {
            b0[n] = *(const v4i*)(sB + boff + n * 2048);
            b1[n] = *(const v4i*)(sB + boff + n * 2048 + 1024);
        }
        // stage half h+3 into slot (h+3)&3 = (h-1)&3 (reads done phase h-1).
        STAGE_A(h + 3);
        STAGE_B(h + 3);
        __builtin_amdgcn_s_barrier();
        asm volatile("s_waitcnt lgkmcnt(0)");
        __builtin_amdgcn_s_setprio(1);
#pragma unroll
        for (int m = 0; m < 4; ++m)
#pragma unroll
            for (int n = 0; n < 2; ++n)
                acc[m][n] = __builtin_amdgcn_mfma_i32_32x32x32_i8(
                    a0[m], b0[n], acc[m][n], 0, 0, 0);
#pragma unroll
        for (int m = 0; m < 4; ++m)
#pragma unroll
            for (int n = 0; n < 2; ++n)
                acc[m][n] = __builtin_amdgcn_mfma_i32_32x32x32_i8(
                    a1[m], b1[n], acc[m][n], 0, 0, 0);
        __builtin_amdgcn_s_setprio(0);
        // counted gate: leave halves h+2, h+3 (8 loads) in flight. Never 0.
        asm volatile("s_waitcnt vmcnt(8)");
        __builtin_amdgcn_s_barrier();
    }

    // Epilogue: 32x32 C/D layout col = lane&31, row = (reg&3)+8*(reg>>2)+4*qh.
    const int row0 = bm * 256 + wr * 128;
    const int col0 = bn * 256 + wc * 64;
    const int rbase = 4 * qh;
#pragma unroll
    for (int m = 0; m < 4; ++m) {
#pragma unroll
        for (int n = 0; n < 2; ++n) {
            const int col = col0 + n * 32 + rl;
            if (col < Ntrue) {
                const float cs = colscale[col];
                const float bs = bias[col];
#pragma unroll
                for (int g = 0; g < 4; ++g) {
#pragma unroll
                    for (int rr = 0; rr < 4; ++rr) {
                        const int row = row0 + m * 32 + rbase + 8 * g + rr;
                        float v = (float)acc[m][n][g * 4 + rr];
                        v = __fmul_rn(v, rowscale[row]);
                        v = __fmul_rn(v, cs);
                        v = __fadd_rn(v, bs);
                        _Float16 hh = (_Float16)v;  // reference rounds to fp16
                        const size_t idx = (size_t)row * ldc + col;
                        if (EPI == 0) ((_Float16*)Cout)[idx] = hh;
                        else ((float*)Cout)[idx] = (float)hh;
                    }
                }
            }
        }
    }
#undef STAGE_A
#undef STAGE_B
}

// -------- exact GELU + per-token dynamic int8 requant (in-place act_q) -------
__global__ __launch_bounds__(256) void gelu_quant(_Float16* __restrict__ fc1,
                                                  float* __restrict__ nscale) {
    __shared__ float gbuf[I_DIM];
    __shared__ float wmax[4];
    const int tid = threadIdx.x, lane = tid & 63, wid = tid >> 6;
    const long t = blockIdx.x;
    const h8* row = (const h8*)(fc1 + t * I_DIM);
    float lmax = 0.f;
    for (int c = tid; c < I_DIM / 8; c += 256) {
        h8 v = row[c];
#pragma unroll
        for (int j = 0; j < 8; ++j) {
            float x = (float)v[j];
            float e = erff(__fdiv_rn(x, 1.41421356237309504880f));
            float g = __fmul_rn(__fmul_rn(0.5f, x), __fadd_rn(1.0f, e));
            gbuf[c * 8 + j] = g;
            lmax = fmaxf(lmax, fabsf(g));
        }
    }
#pragma unroll
    for (int off = 32; off; off >>= 1) lmax = fmaxf(lmax, __shfl_xor(lmax, off, 64));
    if (lane == 0) wmax[wid] = lmax;
    __syncthreads();
    const float gmax = fmaxf(fmaxf(wmax[0], wmax[1]), fmaxf(wmax[2], wmax[3]));
    const float ns = gmax / 127.0f;
    if (tid == 0) nscale[t] = ns;
    unsigned long long* out = (unsigned long long*)(fc1 + t * I_DIM);  // in-place
    for (int c = tid; c < I_DIM / 8; c += 256) {
        unsigned long long pk = 0;
#pragma unroll
        for (int j = 0; j < 8; ++j) {
            float qv = rintf(__fdiv_rn(gbuf[c * 8 + j], ns));
            qv = fminf(fmaxf(qv, -127.f), 127.f);
            pk |= ((unsigned long long)(unsigned char)(signed char)(int)qv) << (8 * j);
        }
        out[c] = pk;
    }
}

extern "C" void kernel_launch(void* const* d_in, const int* in_sizes, int n_in,
                              void* d_out, int out_size, void* d_ws, size_t ws_size,
                              hipStream_t stream) {
    const int* hs = (const int*)d_in[0];        // [B,S,H] int8-in-int32
    const float* scale = (const float*)d_in[1]; // [T]
    const int* w1 = (const int*)d_in[2];        // [I,H]
    const float* w1s = (const float*)d_in[3];   // [I]
    const float* b1 = (const float*)d_in[4];    // [I]
    const int* w2 = (const int*)d_in[5];        // [H,I]
    const float* w2s = (const float*)d_in[6];   // [H]
    const float* b2 = (const float*)d_in[7];    // [H]

    char* ws = (char*)d_ws;
    signed char* xq = (signed char*)ws;                     // 26,214,400 B
    signed char* w1q = xq + (size_t)T_DIM * H_DIM;          // 40,960,000 B
    signed char* w2q = w1q + (size_t)I_DIM * H_DIM;         // 40,960,000 B
    _Float16* fc1h = (_Float16*)(w2q + (size_t)H_DIM * I_DIM);  // chunkT*I fp16
    const size_t fixed = (size_t)T_DIM * H_DIM + 2 * (size_t)I_DIM * H_DIM;

    // choose smallest chunk count whose workspace fits ws_size (deterministic)
    int nc = 1;
    while (nc < 16) {
        size_t need = fixed + ((size_t)T_DIM / nc) * I_DIM * 2 +
                      ((size_t)T_DIM / nc) * 4 + 256;
        if (need <= ws_size) break;
        nc <<= 1;
    }
    const int chunkT = T_DIM / nc;
    float* nscale = (float*)((char*)fc1h + (size_t)chunkT * I_DIM * 2);

    repack_kernel<<<2048, 256, 0, stream>>>(hs, (unsigned int*)xq, (long)T_DIM * H_DIM / 4);
    repack_kernel<<<2048, 256, 0, stream>>>(w1, (unsigned int*)w1q, (long)I_DIM * H_DIM / 4);
    repack_kernel<<<2048, 256, 0, stream>>>(w2, (unsigned int*)w2q, (long)H_DIM * I_DIM / 4);

    const int n2tiles = (H_DIM + 255) / 256;  // 13; last tile col-guarded
    for (int c = 0; c < nc; ++c) {
        const int t0 = c * chunkT;
        gemm_i8_32x32<0><<<dim3(chunkT / 256, I_DIM / 256), 512, 0, stream>>>(
            xq + (size_t)t0 * H_DIM, (long)H_DIM, w1q, (long)H_DIM,
            I_DIM, H_DIM, I_DIM,
            scale + t0, w1s, b1, (void*)fc1h);
        gelu_quant<<<chunkT, 256, 0, stream>>>(fc1h, nscale);
        gemm_i8_32x32<1><<<dim3(chunkT / 256, n2tiles), 512, 0, stream>>>(
            (const signed char*)fc1h, (long)I_DIM * 2, w2q, (long)I_DIM,
            H_DIM, I_DIM, H_DIM,
            nscale, w2s, b2,
            (void*)((float*)d_out + (size_t)t0 * H_DIM));
    }
}

// Round 4
// 1055.359 us; speedup vs baseline: 1.0516x; 1.0516x over previous
//
#include <hip/hip_runtime.h>
#include <hip/hip_bf16.h>
#include <hip/hip_fp16.h>

#define T_DIM 8192
#define H_DIM 3200
#define I_DIM 12800

typedef int v4i __attribute__((ext_vector_type(4)));
typedef int v16i __attribute__((ext_vector_type(16)));
typedef _Float16 h8 __attribute__((ext_vector_type(8)));

__device__ __forceinline__ void gload16(const void* g, void* l) {
    __builtin_amdgcn_global_load_lds(
        (const __attribute__((address_space(1))) unsigned int*)g,
        (__attribute__((address_space(3))) unsigned int*)l, 16, 0, 0);
}

// ---------------- int32 -> int8 repack (memory-bound) ----------------
__global__ __launch_bounds__(256) void repack_kernel(const int* __restrict__ src,
                                                     unsigned int* __restrict__ dst,
                                                     long n4) {
    long i = (long)blockIdx.x * blockDim.x + threadIdx.x;
    long stride = (long)gridDim.x * blockDim.x;
    for (; i < n4; i += stride) {
        int4 v = ((const int4*)src)[i];
        dst[i] = (unsigned int)((v.x & 255) | ((v.y & 255) << 8) |
                                ((v.z & 255) << 16) | ((v.w & 255) << 24));
    }
}

// ---------------- i8 GEMM, C[M][N] = A[M][K] * B[N][K]^T ----------------
// 256x256 tile, 512 threads = 8 waves (2M x 4N), per-wave 128x64 output via
// mfma_i32_32x32x32_i8. ONE barrier per phase (64-byte K-half):
//   { 12 ds_read_b128 ; stage A&B of half h+3 ; setprio1 ; 16 MFMA ;
//     setprio0 ; vmcnt(8) ; s_barrier }
// No mid-phase barrier: waves skew within a phase, so one wave's ds_reads
// overlap another's MFMAs (LDS port 1152 cyc and matrix pipe 1170 cyc per
// phase now run concurrently instead of serially; R3's two-barrier version
// measured 3710 cyc/phase = fully serialized, MfmaUtil 31%).
// Ring-of-4 safety with skew <= 1 phase body: STAGE(h+3) writes slot (h-1)&3;
// all waves' reads of that slot (half h-1) were lgkm-complete before they
// passed the end-of-(h-1) barrier. vmcnt(8) gate before the barrier publishes
// half h+1 for phase h+1 (halves h+2,h+3 = 8 loads stay in flight; never 0).
// Compiler inserts fine-grained lgkm waits for the frag reads (no asm drain).
//
// LDS placement: global_load_lds dest is LINEAR; bijection pi folded into the
// per-lane GLOBAL source so the fragment read is lane-for-lane identical to
// the round-1 pattern that measured 0 bank conflicts:
//   LDS (block, half, r15, col) holds global (row = block*32+((q&1)<<4)+r15,
//   chunk = (half<<1)|(q>>1)),  q = col ^ ((r15>>1)&3).
// strideA/strideB in BYTES. EPI=0: fp16 out. EPI=1: fp32 of fp16-rounded.
// No XCD swizzle (L3-resident regime: it tripled FETCH_SIZE in round 2).
template <int EPI>
__global__ __launch_bounds__(512, 2) void gemm_i8_32x32(
    const signed char* __restrict__ A, long strideA,
    const signed char* __restrict__ B, long strideB,
    int Ntrue, int K, int ldc,
    const float* __restrict__ rowscale, const float* __restrict__ colscale,
    const float* __restrict__ bias, void* __restrict__ Cout) {
    __shared__ signed char lds[131072];
    signed char* ldsA = lds;           // 4 slots x 16384 B (8 blocks of 2 KiB)
    signed char* ldsB = lds + 65536;   // 4 slots x 16384 B

    const int tid = threadIdx.x;
    const int lane = tid & 63, wid = tid >> 6;
    const int wr = wid >> 2, wc = wid & 3;
    const int bm = blockIdx.x, bn = blockIdx.y;
    const long Arow0 = (long)bm * 256;
    const long Bcol0 = (long)bn * 256;

    // Staging: slot = 1024 chunks of 16 B; thread handles ch0 = tid and
    // ch1 = tid+512. LDS dest linear (ch*16); source row/chunk from pi.
    int g_row[2], g_cg[2];
#pragma unroll
    for (int u = 0; u < 2; ++u) {
        const int ch = tid + (u << 9);
        const int block = ch >> 7;
        const int p = ch & 127;
        const int half = (p >> 6) & 1;
        const int p6 = p & 63;
        const int r15 = p6 >> 2;
        const int col = p6 & 3;
        const int q = col ^ ((r15 >> 1) & 3);
        g_row[u] = block * 32 + ((q & 1) << 4) + r15;
        g_cg[u] = (half << 1) | (q >> 1);
    }
    const signed char* Ag0 = A + (Arow0 + g_row[0]) * strideA + g_cg[0] * 16;
    const signed char* Ag1 = A + (Arow0 + g_row[1]) * strideA + g_cg[1] * 16;
    const signed char* Bg0 = B + (Bcol0 + g_row[0]) * strideB + g_cg[0] * 16;
    const signed char* Bg1 = B + (Bcol0 + g_row[1]) * strideB + g_cg[1] * 16;
    const int d0 = tid * 16, d1 = (tid + 512) * 16;

    const int NH = K >> 6;  // number of 64-byte K-halves (phases)

#define STAGE_A(h)                                  \
    {                                               \
        const int hc_ = (h) < NH ? (h) : NH - 1;    \
        const long ko_ = (long)hc_ << 6;            \
        signed char* d_ = ldsA + (((h) & 3) << 14); \
        gload16(Ag0 + ko_, d_ + d0);                \
        gload16(Ag1 + ko_, d_ + d1);                \
    }
#define STAGE_B(h)                                  \
    {                                               \
        const int hc_ = (h) < NH ? (h) : NH - 1;    \
        const long ko_ = (long)hc_ << 6;            \
        signed char* d_ = ldsB + (((h) & 3) << 14); \
        gload16(Bg0 + ko_, d_ + d0);                \
        gload16(Bg1 + ko_, d_ + d1);                \
    }

    // Fragment read offsets (round-1-proven conflict-free pattern per 1 KiB).
    const int rl = lane & 31, qh = lane >> 5;
    const int r15 = rl & 15, qb = rl >> 4;
    const int colr = ((qh << 1) | qb) ^ ((r15 >> 1) & 3);
    const int roff = r15 * 64 + colr * 16;  // within-block, half 0; a1/b1: +1024
    const int aoff = (wr * 4) * 2048 + roff;  // + m*2048, m = 0..3
    const int boff = (wc * 2) * 2048 + roff;  // + n*2048, n = 0..1

    v16i acc[4][2] = {};

    // Prologue: stage halves 0,1,2 (12 loads); gate to 8 -> half 0 resident,
    // halves 1,2 in flight (steady-state invariant entering phase 0).
    STAGE_A(0); STAGE_B(0); STAGE_A(1); STAGE_B(1); STAGE_A(2); STAGE_B(2);
    asm volatile("s_waitcnt vmcnt(8)");
    __builtin_amdgcn_s_barrier();

    for (int h = 0; h < NH; ++h) {
        const signed char* sA = ldsA + ((h & 3) << 14);
        const signed char* sB = ldsB + ((h & 3) << 14);
        v4i a0[4], a1[4], b0[2], b1[2];
#pragma unroll
        for (int m = 0; m < 4; ++m) {
            a0[m] = *(const v4i*)(sA + aoff + m * 2048);
            a1[m] = *(const v4i*)(sA + aoff + m * 2048 + 1024);
        }
#pragma unroll
        for (int n = 0; n < 2; ++n) {
            b0[n] = *(const v4i*)(sB + boff + n * 2048);
            b1[n] = *(const v4i*)(sB + boff + n * 2048 + 1024);
        }
        // stage half h+3 into slot (h+3)&3 = (h-1)&3 (all waves' reads of that
        // slot completed before they passed the previous end-of-phase barrier).
        STAGE_A(h + 3);
        STAGE_B(h + 3);
        __builtin_amdgcn_s_setprio(1);
#pragma unroll
        for (int m = 0; m < 4; ++m)
#pragma unroll
            for (int n = 0; n < 2; ++n)
                acc[m][n] = __builtin_amdgcn_mfma_i32_32x32x32_i8(
                    a0[m], b0[n], acc[m][n], 0, 0, 0);
#pragma unroll
        for (int m = 0; m < 4; ++m)
#pragma unroll
            for (int n = 0; n < 2; ++n)
                acc[m][n] = __builtin_amdgcn_mfma_i32_32x32x32_i8(
                    a1[m], b1[n], acc[m][n], 0, 0, 0);
        __builtin_amdgcn_s_setprio(0);
        // counted gate: retire half h+1; leave halves h+2,h+3 (8 loads) in
        // flight. Then the single per-phase barrier.
        asm volatile("s_waitcnt vmcnt(8)");
        __builtin_amdgcn_s_barrier();
    }

    // Epilogue: 32x32 C/D layout col = lane&31, row = (reg&3)+8*(reg>>2)+4*qh.
    const int row0 = bm * 256 + wr * 128;
    const int col0 = bn * 256 + wc * 64;
    const int rbase = 4 * qh;
#pragma unroll
    for (int m = 0; m < 4; ++m) {
#pragma unroll
        for (int n = 0; n < 2; ++n) {
            const int col = col0 + n * 32 + rl;
            if (col < Ntrue) {
                const float cs = colscale[col];
                const float bs = bias[col];
#pragma unroll
                for (int g = 0; g < 4; ++g) {
#pragma unroll
                    for (int rr = 0; rr < 4; ++rr) {
                        const int row = row0 + m * 32 + rbase + 8 * g + rr;
                        float v = (float)acc[m][n][g * 4 + rr];
                        v = __fmul_rn(v, rowscale[row]);
                        v = __fmul_rn(v, cs);
                        v = __fadd_rn(v, bs);
                        _Float16 hh = (_Float16)v;  // reference rounds to fp16
                        const size_t idx = (size_t)row * ldc + col;
                        if (EPI == 0) ((_Float16*)Cout)[idx] = hh;
                        else ((float*)Cout)[idx] = (float)hh;
                    }
                }
            }
        }
    }
#undef STAGE_A
#undef STAGE_B
}

// -------- exact GELU + per-token dynamic int8 requant (in-place act_q) -------
__global__ __launch_bounds__(256) void gelu_quant(_Float16* __restrict__ fc1,
                                                  float* __restrict__ nscale) {
    __shared__ float gbuf[I_DIM];
    __shared__ float wmax[4];
    const int tid = threadIdx.x, lane = tid & 63, wid = tid >> 6;
    const long t = blockIdx.x;
    const h8* row = (const h8*)(fc1 + t * I_DIM);
    float lmax = 0.f;
    for (int c = tid; c < I_DIM / 8; c += 256) {
        h8 v = row[c];
#pragma unroll
        for (int j = 0; j < 8; ++j) {
            float x = (float)v[j];
            float e = erff(__fdiv_rn(x, 1.41421356237309504880f));
            float g = __fmul_rn(__fmul_rn(0.5f, x), __fadd_rn(1.0f, e));
            gbuf[c * 8 + j] = g;
            lmax = fmaxf(lmax, fabsf(g));
        }
    }
#pragma unroll
    for (int off = 32; off; off >>= 1) lmax = fmaxf(lmax, __shfl_xor(lmax, off, 64));
    if (lane == 0) wmax[wid] = lmax;
    __syncthreads();
    const float gmax = fmaxf(fmaxf(wmax[0], wmax[1]), fmaxf(wmax[2], wmax[3]));
    const float ns = gmax / 127.0f;
    if (tid == 0) nscale[t] = ns;
    unsigned long long* out = (unsigned long long*)(fc1 + t * I_DIM);  // in-place
    for (int c = tid; c < I_DIM / 8; c += 256) {
        unsigned long long pk = 0;
#pragma unroll
        for (int j = 0; j < 8; ++j) {
            float qv = rintf(__fdiv_rn(gbuf[c * 8 + j], ns));
            qv = fminf(fmaxf(qv, -127.f), 127.f);
            pk |= ((unsigned long long)(unsigned char)(signed char)(int)qv) << (8 * j);
        }
        out[c] = pk;
    }
}

extern "C" void kernel_launch(void* const* d_in, const int* in_sizes, int n_in,
                              void* d_out, int out_size, void* d_ws, size_t ws_size,
                              hipStream_t stream) {
    const int* hs = (const int*)d_in[0];        // [B,S,H] int8-in-int32
    const float* scale = (const float*)d_in[1]; // [T]
    const int* w1 = (const int*)d_in[2];        // [I,H]
    const float* w1s = (const float*)d_in[3];   // [I]
    const float* b1 = (const float*)d_in[4];    // [I]
    const int* w2 = (const int*)d_in[5];        // [H,I]
    const float* w2s = (const float*)d_in[6];   // [H]
    const float* b2 = (const float*)d_in[7];    // [H]

    char* ws = (char*)d_ws;
    signed char* xq = (signed char*)ws;                     // 26,214,400 B
    signed char* w1q = xq + (size_t)T_DIM * H_DIM;          // 40,960,000 B
    signed char* w2q = w1q + (size_t)I_DIM * H_DIM;         // 40,960,000 B
    _Float16* fc1h = (_Float16*)(w2q + (size_t)H_DIM * I_DIM);  // chunkT*I fp16
    const size_t fixed = (size_t)T_DIM * H_DIM + 2 * (size_t)I_DIM * H_DIM;

    // choose smallest chunk count whose workspace fits ws_size (deterministic)
    int nc = 1;
    while (nc < 16) {
        size_t need = fixed + ((size_t)T_DIM / nc) * I_DIM * 2 +
                      ((size_t)T_DIM / nc) * 4 + 256;
        if (need <= ws_size) break;
        nc <<= 1;
    }
    const int chunkT = T_DIM / nc;
    float* nscale = (float*)((char*)fc1h + (size_t)chunkT * I_DIM * 2);

    repack_kernel<<<2048, 256, 0, stream>>>(hs, (unsigned int*)xq, (long)T_DIM * H_DIM / 4);
    repack_kernel<<<2048, 256, 0, stream>>>(w1, (unsigned int*)w1q, (long)I_DIM * H_DIM / 4);
    repack_kernel<<<2048, 256, 0, stream>>>(w2, (unsigned int*)w2q, (long)H_DIM * I_DIM / 4);

    const int n2tiles = (H_DIM + 255) / 256;  // 13; last tile col-guarded
    for (int c = 0; c < nc; ++c) {
        const int t0 = c * chunkT;
        gemm_i8_32x32<0><<<dim3(chunkT / 256, I_DIM / 256), 512, 0, stream>>>(
            xq + (size_t)t0 * H_DIM, (long)H_DIM, w1q, (long)H_DIM,
            I_DIM, H_DIM, I_DIM,
            scale + t0, w1s, b1, (void*)fc1h);
        gelu_quant<<<chunkT, 256, 0, stream>>>(fc1h, nscale);
        gemm_i8_32x32<1><<<dim3(chunkT / 256, n2tiles), 512, 0, stream>>>(
            (const signed char*)fc1h, (long)I_DIM * 2, w2q, (long)I_DIM,
            H_DIM, I_DIM, H_DIM,
            nscale, w2s, b2,
            (void*)((float*)d_out + (size_t)t0 * H_DIM));
    }
}